// Round 11
// baseline (604.686 us; speedup 1.0000x reference)
//
#include <hip/hip_runtime.h>
#include <hip/hip_bf16.h>

typedef __bf16 bf16;
typedef __attribute__((ext_vector_type(4))) float f32x4;
typedef __attribute__((ext_vector_type(8))) __bf16 bf16x8;
typedef __attribute__((ext_vector_type(4))) __bf16 bf16x4;

// async global->LDS, 16B per lane; LDS dest must be wave-uniform base + lane*16
static __device__ __forceinline__ void gl16(const void* g, void* l) {
  __builtin_amdgcn_global_load_lds((const __attribute__((address_space(1))) void*)g,
                                   (__attribute__((address_space(3))) void*)l, 16, 0, 0);
}
// fragment read from a [*][64] bf16 tile, 16B-unit XOR swizzle by (row&7)
static __device__ __forceinline__ bf16x8 frag(const bf16* tile, int row, int kb) {
  return *(const bf16x8*)(tile + row * 64 + ((((kb) >> 3) ^ (row & 7)) << 3));
}

// ---------------------------------------------------------------------------
// Weight prepass: 4x [256][256] f32 -> bf16 row-major.
// ---------------------------------------------------------------------------
__global__ void wpre(const float* __restrict__ w0, const float* __restrict__ w1,
                     const float* __restrict__ w2, const float* __restrict__ w3,
                     bf16* __restrict__ dst) {
  const float* srcs[4] = {w0, w1, w2, w3};
  const float* s = srcs[blockIdx.y];
  bf16* d = dst + (size_t)blockIdx.y * 65536;
  int base = blockIdx.x * 2048 + threadIdx.x * 8;
  f32x4 a = *(const f32x4*)(s + base);
  f32x4 b = *(const f32x4*)(s + base + 4);
  bf16x8 v = {(bf16)a[0], (bf16)a[1], (bf16)a[2], (bf16)a[3],
              (bf16)b[0], (bf16)b[1], (bf16)b[2], (bf16)b[3]};
  *(bf16x8*)(d + base) = v;
}

// ===========================================================================
// Fused Q-projection + score (unchanged from round 8 — at structure ceiling).
// ===========================================================================
__global__ __launch_bounds__(256, 3)
void qscore(const float* __restrict__ query, const bf16* __restrict__ Wq,
            const float* __restrict__ bq, const bf16* __restrict__ Kpm,
            float* __restrict__ score) {
  __shared__ alignas(16) char smem[64 * 264 * 2];
  const int t = threadIdx.x;
  const int b = blockIdx.z;
  const int p0 = blockIdx.x * 64;
  const int w = t >> 6, l = t & 63;
  const int lrow = l & 15, ksel = l >> 4;
  const int pq = t & 15, cq = t >> 4;
  const float* actb = query + (size_t)b * 256 * 6400;

  auto Bt = [&](int buf) { return (bf16*)(smem + buf * 8192); };

  f32x4 Ar[4];
  auto ALOAD = [&](int kt) {
    const int k0 = kt * 64;
#pragma unroll
    for (int j = 0; j < 4; ++j)
      Ar[j] = *(const f32x4*)(actb + (size_t)(k0 + cq * 4 + j) * 6400 + p0 + pq * 4);
  };
  auto ASTORE = [&](int buf) {
    bf16* tile = Bt(buf);
#pragma unroll
    for (int e = 0; e < 4; ++e) {
      int row = pq * 4 + e;
      bf16x4 v = {(bf16)Ar[0][e], (bf16)Ar[1][e], (bf16)Ar[2][e], (bf16)Ar[3][e]};
      *(bf16x4*)(tile + row * 64 + ((((cq >> 1) ^ (row & 7)) << 3) | ((cq & 1) << 2))) = v;
    }
  };

  f32x4 acc[4][4];
#pragma unroll
  for (int i = 0; i < 4; ++i)
#pragma unroll
    for (int j = 0; j < 4; ++j) acc[i][j] = (f32x4){0.f, 0.f, 0.f, 0.f};

  auto COMPUTE = [&](int kt, int buf) {
    const int k0 = kt * 64;
    bf16x8 af[4][2];
#pragma unroll
    for (int mi = 0; mi < 4; ++mi)
#pragma unroll
      for (int kk = 0; kk < 2; ++kk)
        af[mi][kk] = *(const bf16x8*)(Wq + (size_t)(w * 64 + mi * 16 + lrow) * 256 +
                                      k0 + kk * 32 + ksel * 8);
    bf16x8 bv[4][2];
#pragma unroll
    for (int ni = 0; ni < 4; ++ni)
#pragma unroll
      for (int kk = 0; kk < 2; ++kk)
        bv[ni][kk] = frag(Bt(buf), ni * 16 + lrow, kk * 32 + ksel * 8);
#pragma unroll
    for (int kk = 0; kk < 2; ++kk)
#pragma unroll
      for (int mi = 0; mi < 4; ++mi)
#pragma unroll
        for (int ni = 0; ni < 4; ++ni)
          acc[mi][ni] = __builtin_amdgcn_mfma_f32_16x16x32_bf16(af[mi][kk], bv[ni][kk],
                                                                acc[mi][ni], 0, 0, 0);
  };

  ALOAD(0);
  ASTORE(0);
  __syncthreads();
#pragma unroll
  for (int kt = 0; kt < 4; ++kt) {
    if (kt < 3) ALOAD(kt + 1);
    COMPUTE(kt, kt & 1);
    if (kt < 3) ASTORE((kt + 1) & 1);
    __syncthreads();
  }

  __syncthreads();
  bf16* Qs = (bf16*)smem;
#pragma unroll
  for (int mi = 0; mi < 4; ++mi) {
#pragma unroll
    for (int r = 0; r < 4; ++r) {
      int o = w * 64 + mi * 16 + ksel * 4 + r;
      float bvf = bq[o];
#pragma unroll
      for (int ni = 0; ni < 4; ++ni) {
        int px = ni * 16 + lrow;
        Qs[px * 264 + o] = (bf16)(acc[mi][ni][r] + bvf);
      }
    }
  }
  __syncthreads();

  {
    int pl = t & 63, hd = t >> 6;
    int p = p0 + pl;
    int x = p / 80, y = p % 80;
    float cx = 0.5f * x - 0.25f;
    int ix = (int)floorf(cx);
    float wx1 = cx - ix;
    int x0 = ix < 0 ? 0 : ix, x1 = (ix + 1 > 39) ? 39 : ix + 1;
    float cy = 0.5f * y - 0.25f;
    int iy = (int)floorf(cy);
    float wy1 = cy - iy;
    int y0 = iy < 0 ? 0 : iy, y1 = (iy + 1 > 39) ? 39 : iy + 1;
    float w00 = (1.f - wx1) * (1.f - wy1), w01 = (1.f - wx1) * wy1;
    float w10 = wx1 * (1.f - wy1), w11 = wx1 * wy1;
    const bf16* k00 = Kpm + ((size_t)b * 1600 + x0 * 40 + y0) * 256 + hd * 64;
    const bf16* k01 = Kpm + ((size_t)b * 1600 + x0 * 40 + y1) * 256 + hd * 64;
    const bf16* k10 = Kpm + ((size_t)b * 1600 + x1 * 40 + y0) * 256 + hd * 64;
    const bf16* k11 = Kpm + ((size_t)b * 1600 + x1 * 40 + y1) * 256 + hd * 64;
    float dot = 0.f;
#pragma unroll
    for (int i = 0; i < 8; ++i) {
      bf16x8 qv = *(const bf16x8*)(Qs + pl * 264 + hd * 64 + i * 8);
      bf16x8 a = *(const bf16x8*)(k00 + i * 8);
      bf16x8 c = *(const bf16x8*)(k01 + i * 8);
      bf16x8 d = *(const bf16x8*)(k10 + i * 8);
      bf16x8 e = *(const bf16x8*)(k11 + i * 8);
#pragma unroll
      for (int j = 0; j < 8; ++j) {
        float kup = w00 * (float)a[j] + w01 * (float)c[j] + w10 * (float)d[j] + w11 * (float)e[j];
        dot += (float)qv[j] * kup;
      }
    }
    score[((size_t)b * 4 + hd) * 6400 + p] = dot * 0.0625f;
  }
}

// ---------------------------------------------------------------------------
// K+V projection (unchanged from round 7/8).
// ---------------------------------------------------------------------------
__global__ __launch_bounds__(512, 1)
void kv_gemm(const float* __restrict__ key,
             const bf16* __restrict__ Wk, const float* __restrict__ bk, bf16* __restrict__ Kpm,
             const bf16* __restrict__ Wv, const float* __restrict__ bv, bf16* __restrict__ Vpm) {
  __shared__ alignas(16) char smem[65536];
  const int P = 1600;
  const int t = threadIdx.x;
  const int b = blockIdx.z;
  const int m0 = blockIdx.x * 128;
  const int sel = blockIdx.y >> 1;
  const int n0 = (blockIdx.y & 1) * 128;
  const bf16* W = sel ? Wv : Wk;
  const float* bias = sel ? bv : bk;
  bf16* out = sel ? Vpm : Kpm;
  const int w = t >> 6, l = t & 63;
  const int wr = w & 1, wc = w >> 1;
  const int lrow = l & 15, koff = (l >> 4) * 8;
  const int up = t & 31, uk = t >> 5;
  const float* actb = key + (size_t)b * 256 * P;

  f32x4 Ar[4];
  f32x4 acc[4][2];
#pragma unroll
  for (int i = 0; i < 4; ++i)
#pragma unroll
    for (int j = 0; j < 2; ++j) acc[i][j] = (f32x4){0.f, 0.f, 0.f, 0.f};

  auto Ab = [&](int buf) { return (bf16*)(smem + buf * 16384); };
  auto Bb = [&](int buf) { return (bf16*)(smem + 32768 + buf * 16384); };

  auto GLOADB = [&](int kt, int buf) {
    const int k0 = kt * 64;
#pragma unroll
    for (int call = 0; call < 2; ++call) {
      int idx = call * 512 + t;
      int row = idx >> 3, u = idx & 7;
      gl16(W + (size_t)(n0 + row) * 256 + k0 + ((u ^ (row & 7)) << 3), Bb(buf) + idx * 8);
    }
  };
  auto ALOAD = [&](int kt) {
    const int k0 = kt * 64;
    int ps = m0 + up * 4;
    if (ps > P - 4) ps = P - 4;
#pragma unroll
    for (int j = 0; j < 4; ++j)
      Ar[j] = *(const f32x4*)(actb + (size_t)(k0 + uk * 4 + j) * P + ps);
  };
  auto ASTORE = [&](int buf) {
#pragma unroll
    for (int j = 0; j < 4; ++j) {
      int row = up * 4 + j;
      int cs = (uk * 4) ^ ((row & 7) << 3);
      bf16x4 v = {(bf16)Ar[0][j], (bf16)Ar[1][j], (bf16)Ar[2][j], (bf16)Ar[3][j]};
      *(bf16x4*)(Ab(buf) + row * 64 + cs) = v;
    }
  };
  auto COMPUTE = [&](int buf) {
#pragma unroll
    for (int kk = 0; kk < 2; ++kk) {
      bf16x8 af[4], bvv[2];
      const int kb = kk * 32 + koff;
#pragma unroll
      for (int i = 0; i < 4; ++i) af[i] = frag(Ab(buf), wr * 64 + i * 16 + lrow, kb);
#pragma unroll
      for (int j = 0; j < 2; ++j) bvv[j] = frag(Bb(buf), wc * 32 + j * 16 + lrow, kb);
#pragma unroll
      for (int i = 0; i < 4; ++i)
#pragma unroll
        for (int j = 0; j < 2; ++j)
          acc[i][j] = __builtin_amdgcn_mfma_f32_16x16x32_bf16(af[i], bvv[j], acc[i][j], 0, 0, 0);
    }
  };

  GLOADB(0, 0);
  ALOAD(0);
  ASTORE(0);
  __syncthreads();
#pragma unroll
  for (int kt = 0; kt < 4; ++kt) {
    const int cur = kt & 1;
    if (kt < 3) { GLOADB(kt + 1, cur ^ 1); ALOAD(kt + 1); }
    __builtin_amdgcn_sched_barrier(0);
    COMPUTE(cur);
    if (kt < 3) ASTORE(cur ^ 1);
    __syncthreads();
  }

  bf16* Sc = (bf16*)smem;
#pragma unroll
  for (int mi = 0; mi < 4; ++mi) {
#pragma unroll
    for (int ni = 0; ni < 2; ++ni) {
      int ch = wc * 32 + ni * 16 + (l & 15);
      float bvf = bias[n0 + ch];
#pragma unroll
      for (int r = 0; r < 4; ++r) {
        int p = wr * 64 + mi * 16 + (l >> 4) * 4 + r;
        Sc[p * 136 + ch] = (bf16)(acc[mi][ni][r] + bvf);
      }
    }
  }
  __syncthreads();
  bf16* ob = out + (size_t)b * P * 256;
#pragma unroll
  for (int pass = 0; pass < 4; ++pass) {
    int unit = pass * 512 + t;
    int row = unit >> 4, cu = unit & 15;
    if (m0 + row < P) {
      bf16x8 v = *(const bf16x8*)(Sc + row * 136 + cu * 8);
      *(bf16x8*)(ob + (size_t)(m0 + row) * 256 + n0 + cu * 8) = v;
    }
  }
}

// ---------------------------------------------------------------------------
// In-place column softmax over x (per b,hd,y), x4 (R2 sum) folded in.
// ---------------------------------------------------------------------------
__global__ void smax_kernel(float* __restrict__ score) {
  __shared__ float s[6400];
  const int hd = blockIdx.x, b = blockIdx.y, t = threadIdx.x;
  float* buf = score + ((size_t)b * 4 + hd) * 6400;
  for (int i = t; i < 6400; i += 256) s[i] = buf[i];
  __syncthreads();
  if (t < 80) {
    const int y = t;
    float m = -1e30f;
    for (int x = 0; x < 80; ++x) m = fmaxf(m, s[x * 80 + y]);
    float sum = 0.f;
    for (int x = 0; x < 80; ++x) {
      float e = __expf(s[x * 80 + y] - m);
      s[x * 80 + y] = e;
      sum += e;
    }
    float inv = 4.0f / sum;
    for (int x = 0; x < 80; ++x) buf[x * 80 + y] = s[x * 80 + y] * inv;
  }
}

// ===========================================================================
// Uv[b][hd][o][q] = sum_{c<64} wo[o][hd*64+c] * V[b][q][hd*64+c]  (bf16)
// K=64 GEMM: A = wo rows (L2-direct), B = Vpm rows staged via gl16 with
// source-XOR swizzle (conflict-free frag reads). Block: 256 o x 64 q, 4 waves.
// ===========================================================================
__global__ __launch_bounds__(256, 4)
void uv_gemm(const bf16* __restrict__ Vpm, const bf16* __restrict__ Wo,
             bf16* __restrict__ Uv) {
  __shared__ alignas(16) bf16 Vt[64 * 64];  // 8KB [q][c], src-XOR swizzled
  const int t = threadIdx.x;
  const int b = blockIdx.z;
  const int hd = blockIdx.y;
  const int q0 = blockIdx.x * 64;
  const int w = t >> 6, l = t & 63;
  const int lrow = l & 15, ksel = l >> 4;

  const bf16* vsrc = Vpm + ((size_t)b * 1600 + q0) * 256 + hd * 64;
#pragma unroll
  for (int call = 0; call < 2; ++call) {
    int idx = (w * 2 + call) * 64 + l;
    int q = idx >> 3, u = idx & 7;
    gl16(vsrc + (size_t)q * 256 + ((u ^ (q & 7)) << 3), Vt + idx * 8);
  }
  asm volatile("s_waitcnt vmcnt(0)" ::: "memory");
  __syncthreads();

  f32x4 acc[4][4];
#pragma unroll
  for (int i = 0; i < 4; ++i)
#pragma unroll
    for (int j = 0; j < 4; ++j) acc[i][j] = (f32x4){0.f, 0.f, 0.f, 0.f};

#pragma unroll
  for (int kk = 0; kk < 2; ++kk) {
    bf16x8 af[4], bv[4];
#pragma unroll
    for (int mi = 0; mi < 4; ++mi)
      af[mi] = *(const bf16x8*)(Wo + (size_t)(w * 64 + mi * 16 + lrow) * 256 +
                                hd * 64 + kk * 32 + ksel * 8);
#pragma unroll
    for (int ni = 0; ni < 4; ++ni)
      bv[ni] = frag(Vt, ni * 16 + lrow, kk * 32 + ksel * 8);
#pragma unroll
    for (int mi = 0; mi < 4; ++mi)
#pragma unroll
      for (int ni = 0; ni < 4; ++ni)
        acc[mi][ni] = __builtin_amdgcn_mfma_f32_16x16x32_bf16(af[mi], bv[ni], acc[mi][ni], 0, 0, 0);
  }

  bf16* ob = Uv + ((size_t)(b * 4 + hd)) * 256 * 1600;
#pragma unroll
  for (int mi = 0; mi < 4; ++mi) {
#pragma unroll
    for (int ni = 0; ni < 4; ++ni) {
#pragma unroll
      for (int r = 0; r < 4; ++r) {
        int o = w * 64 + mi * 16 + ksel * 4 + r;
        int q = q0 + ni * 16 + lrow;
        ob[(size_t)o * 1600 + q] = (bf16)acc[mi][ni][r];
      }
    }
  }
}

// ===========================================================================
// d_out[b][o][p] = bo[o] + sum_hd attn[b][hd][p] * bilinear(Uv[b][hd][o])(p)
// Block (o-tile of 4, b). Stage 16 Uv rows (51.2KB LDS). Threads t<160:
// (x = t%80, oh = t/80); x-interp rows kept in registers (xc[40], static
// y-indexing via full unroll); contiguous f32x4 writes along p.
// ===========================================================================
__global__ __launch_bounds__(256, 2)
void combine(const bf16* __restrict__ Uv, const float* __restrict__ attn,
             const float* __restrict__ bo, float* __restrict__ out) {
  __shared__ bf16 Us[16 * 1600];  // [hd*4+oo][q]
  const int t = threadIdx.x;
  const int b = blockIdx.y;
  const int o0 = blockIdx.x * 4;

  const bf16* usrc = Uv + (size_t)(b * 4) * 256 * 1600;
#pragma unroll
  for (int i = 0; i < 13; ++i) {
    int idx = i * 256 + t;
    if (idx < 3200) {
      int row = idx / 200, u = idx % 200;
      int hd = row >> 2, oo = row & 3;
      bf16x8 v = *(const bf16x8*)(usrc + ((size_t)hd * 256 + o0 + oo) * 1600 + u * 8);
      *(bf16x8*)(Us + row * 1600 + u * 8) = v;
    }
  }
  __syncthreads();
  if (t >= 160) return;
  const int x = t % 80, oh = t / 80;

  float cx = 0.5f * x - 0.25f;
  int ix = (int)floorf(cx);
  float wx1 = cx - ix, wx0 = 1.f - wx1;
  int x0 = ix < 0 ? 0 : ix, x1 = (ix + 1 > 39) ? 39 : ix + 1;

  const float* attb = attn + (size_t)b * 4 * 6400 + x * 80;

  for (int oo2 = 0; oo2 < 2; ++oo2) {
    int oo = oh * 2 + oo2;
    float acc[80];
#pragma unroll
    for (int y = 0; y < 80; ++y) acc[y] = 0.f;

#pragma unroll
    for (int hd = 0; hd < 4; ++hd) {
      const bf16* r0 = Us + (hd * 4 + oo) * 1600 + x0 * 40;
      const bf16* r1 = Us + (hd * 4 + oo) * 1600 + x1 * 40;
      float xc[40];
#pragma unroll
      for (int i = 0; i < 5; ++i) {
        bf16x8 a = *(const bf16x8*)(r0 + i * 8);
        bf16x8 c = *(const bf16x8*)(r1 + i * 8);
#pragma unroll
        for (int j = 0; j < 8; ++j)
          xc[i * 8 + j] = wx0 * (float)a[j] + wx1 * (float)c[j];
      }
      const float* ah = attb + hd * 6400;
#pragma unroll
      for (int yc = 0; yc < 80; yc += 16) {
        f32x4 at0 = *(const f32x4*)(ah + yc);
        f32x4 at1 = *(const f32x4*)(ah + yc + 4);
        f32x4 at2 = *(const f32x4*)(ah + yc + 8);
        f32x4 at3 = *(const f32x4*)(ah + yc + 12);
        float at[16] = {at0[0], at0[1], at0[2], at0[3], at1[0], at1[1], at1[2], at1[3],
                        at2[0], at2[1], at2[2], at2[3], at3[0], at3[1], at3[2], at3[3]};
#pragma unroll
        for (int yy = 0; yy < 16; ++yy) {
          const int y = yc + yy;
          const int iy = (y == 0) ? -1 : ((y - 1) >> 1);
          const int lo = iy < 0 ? 0 : iy;
          const int hi = (iy + 1 > 39) ? 39 : iy + 1;
          float wyh = (0.5f * y - 0.25f) - iy;
          acc[y] += at[yy] * ((1.f - wyh) * xc[lo] + wyh * xc[hi]);
        }
      }
    }
    float bias = bo[o0 + oo];
    float* op = out + ((size_t)b * 256 + o0 + oo) * 6400 + x * 80;
#pragma unroll
    for (int y = 0; y < 80; y += 4) {
      f32x4 v = {acc[y] + bias, acc[y + 1] + bias, acc[y + 2] + bias, acc[y + 3] + bias};
      *(f32x4*)(op + y) = v;
    }
  }
}

// ---------------------------------------------------------------------------
extern "C" void kernel_launch(void* const* d_in, const int* in_sizes, int n_in,
                              void* d_out, int out_size, void* d_ws, size_t ws_size,
                              hipStream_t stream) {
  const float* query = (const float*)d_in[0];
  const float* key   = (const float*)d_in[1];
  const float* wq    = (const float*)d_in[2];
  const float* bq    = (const float*)d_in[3];
  const float* wk    = (const float*)d_in[4];
  const float* bk    = (const float*)d_in[5];
  const float* wv    = (const float*)d_in[6];
  const float* bv    = (const float*)d_in[7];
  const float* wo    = (const float*)d_in[8];
  const float* bo    = (const float*)d_in[9];

  // ws layout (85.7 MB): Uv | Kpm | Vpm | score(+attn in-place) | Wb
  char* ws = (char*)d_ws;
  bf16*  Uv    = (bf16*)(ws);              // 52,428,800 B  [b][hd][o][q]
  bf16*  Kpm   = (bf16*)(ws + 52428800);   // 13,107,200 B
  bf16*  Vpm   = (bf16*)(ws + 65536000);   // 13,107,200 B
  float* score = (float*)(ws + 78643200);  //  6,553,600 B
  bf16*  Wb    = (bf16*)(ws + 85196800);   //    524,288 B: wq,wk,wv,wo bf16
  bf16* wqb = Wb, *wkb = Wb + 65536, *wvb = Wb + 131072, *wob = Wb + 196608;

  wpre<<<dim3(32, 4), 256, 0, stream>>>(wq, wk, wv, wo, Wb);
  kv_gemm<<<dim3(13, 4, 16), 512, 0, stream>>>(key, wkb, bk, Kpm, wvb, bv, Vpm);
  qscore<<<dim3(100, 1, 16), 256, 0, stream>>>(query, wqb, bq, Kpm, score);
  smax_kernel<<<dim3(4, 16), 256, 0, stream>>>(score);
  uv_gemm<<<dim3(25, 4, 16), 256, 0, stream>>>(Vpm, wob, Uv);
  combine<<<dim3(64, 16), 256, 0, stream>>>(Uv, score, bo, (float*)d_out);
}

// Round 12
// 273.850 us; speedup vs baseline: 2.2081x; 2.2081x over previous
//
#include <hip/hip_runtime.h>
#include <hip/hip_bf16.h>

typedef __bf16 bf16;
typedef __attribute__((ext_vector_type(4))) float f32x4;
typedef __attribute__((ext_vector_type(8))) __bf16 bf16x8;
typedef __attribute__((ext_vector_type(4))) __bf16 bf16x4;

// async global->LDS, 16B per lane; LDS dest must be wave-uniform base + lane*16
static __device__ __forceinline__ void gl16(const void* g, void* l) {
  __builtin_amdgcn_global_load_lds((const __attribute__((address_space(1))) void*)g,
                                   (__attribute__((address_space(3))) void*)l, 16, 0, 0);
}
// fragment read from a [*][64] bf16 tile, 16B-unit XOR swizzle by (row&7)
static __device__ __forceinline__ bf16x8 frag(const bf16* tile, int row, int kb) {
  return *(const bf16x8*)(tile + row * 64 + ((((kb) >> 3) ^ (row & 7)) << 3));
}

// ---------------------------------------------------------------------------
// Weight prepass: 4x [256][256] f32 -> bf16 row-major.
// ---------------------------------------------------------------------------
__global__ void wpre(const float* __restrict__ w0, const float* __restrict__ w1,
                     const float* __restrict__ w2, const float* __restrict__ w3,
                     bf16* __restrict__ dst) {
  const float* srcs[4] = {w0, w1, w2, w3};
  const float* s = srcs[blockIdx.y];
  bf16* d = dst + (size_t)blockIdx.y * 65536;
  int base = blockIdx.x * 2048 + threadIdx.x * 8;
  f32x4 a = *(const f32x4*)(s + base);
  f32x4 b = *(const f32x4*)(s + base + 4);
  bf16x8 v = {(bf16)a[0], (bf16)a[1], (bf16)a[2], (bf16)a[3],
              (bf16)b[0], (bf16)b[1], (bf16)b[2], (bf16)b[3]};
  *(bf16x8*)(d + base) = v;
}

// ===========================================================================
// Fused Q-projection + score (unchanged — at structure ceiling).
// ===========================================================================
__global__ __launch_bounds__(256, 3)
void qscore(const float* __restrict__ query, const bf16* __restrict__ Wq,
            const float* __restrict__ bq, const bf16* __restrict__ Kpm,
            float* __restrict__ score) {
  __shared__ alignas(16) char smem[64 * 264 * 2];
  const int t = threadIdx.x;
  const int b = blockIdx.z;
  const int p0 = blockIdx.x * 64;
  const int w = t >> 6, l = t & 63;
  const int lrow = l & 15, ksel = l >> 4;
  const int pq = t & 15, cq = t >> 4;
  const float* actb = query + (size_t)b * 256 * 6400;

  auto Bt = [&](int buf) { return (bf16*)(smem + buf * 8192); };

  f32x4 Ar[4];
  auto ALOAD = [&](int kt) {
    const int k0 = kt * 64;
#pragma unroll
    for (int j = 0; j < 4; ++j)
      Ar[j] = *(const f32x4*)(actb + (size_t)(k0 + cq * 4 + j) * 6400 + p0 + pq * 4);
  };
  auto ASTORE = [&](int buf) {
    bf16* tile = Bt(buf);
#pragma unroll
    for (int e = 0; e < 4; ++e) {
      int row = pq * 4 + e;
      bf16x4 v = {(bf16)Ar[0][e], (bf16)Ar[1][e], (bf16)Ar[2][e], (bf16)Ar[3][e]};
      *(bf16x4*)(tile + row * 64 + ((((cq >> 1) ^ (row & 7)) << 3) | ((cq & 1) << 2))) = v;
    }
  };

  f32x4 acc[4][4];
#pragma unroll
  for (int i = 0; i < 4; ++i)
#pragma unroll
    for (int j = 0; j < 4; ++j) acc[i][j] = (f32x4){0.f, 0.f, 0.f, 0.f};

  auto COMPUTE = [&](int kt, int buf) {
    const int k0 = kt * 64;
    bf16x8 af[4][2];
#pragma unroll
    for (int mi = 0; mi < 4; ++mi)
#pragma unroll
      for (int kk = 0; kk < 2; ++kk)
        af[mi][kk] = *(const bf16x8*)(Wq + (size_t)(w * 64 + mi * 16 + lrow) * 256 +
                                      k0 + kk * 32 + ksel * 8);
    bf16x8 bv[4][2];
#pragma unroll
    for (int ni = 0; ni < 4; ++ni)
#pragma unroll
      for (int kk = 0; kk < 2; ++kk)
        bv[ni][kk] = frag(Bt(buf), ni * 16 + lrow, kk * 32 + ksel * 8);
#pragma unroll
    for (int kk = 0; kk < 2; ++kk)
#pragma unroll
      for (int mi = 0; mi < 4; ++mi)
#pragma unroll
        for (int ni = 0; ni < 4; ++ni)
          acc[mi][ni] = __builtin_amdgcn_mfma_f32_16x16x32_bf16(af[mi][kk], bv[ni][kk],
                                                                acc[mi][ni], 0, 0, 0);
  };

  ALOAD(0);
  ASTORE(0);
  __syncthreads();
#pragma unroll
  for (int kt = 0; kt < 4; ++kt) {
    if (kt < 3) ALOAD(kt + 1);
    COMPUTE(kt, kt & 1);
    if (kt < 3) ASTORE((kt + 1) & 1);
    __syncthreads();
  }

  __syncthreads();
  bf16* Qs = (bf16*)smem;
#pragma unroll
  for (int mi = 0; mi < 4; ++mi) {
#pragma unroll
    for (int r = 0; r < 4; ++r) {
      int o = w * 64 + mi * 16 + ksel * 4 + r;
      float bvf = bq[o];
#pragma unroll
      for (int ni = 0; ni < 4; ++ni) {
        int px = ni * 16 + lrow;
        Qs[px * 264 + o] = (bf16)(acc[mi][ni][r] + bvf);
      }
    }
  }
  __syncthreads();

  {
    int pl = t & 63, hd = t >> 6;
    int p = p0 + pl;
    int x = p / 80, y = p % 80;
    float cx = 0.5f * x - 0.25f;
    int ix = (int)floorf(cx);
    float wx1 = cx - ix;
    int x0 = ix < 0 ? 0 : ix, x1 = (ix + 1 > 39) ? 39 : ix + 1;
    float cy = 0.5f * y - 0.25f;
    int iy = (int)floorf(cy);
    float wy1 = cy - iy;
    int y0 = iy < 0 ? 0 : iy, y1 = (iy + 1 > 39) ? 39 : iy + 1;
    float w00 = (1.f - wx1) * (1.f - wy1), w01 = (1.f - wx1) * wy1;
    float w10 = wx1 * (1.f - wy1), w11 = wx1 * wy1;
    const bf16* k00 = Kpm + ((size_t)b * 1600 + x0 * 40 + y0) * 256 + hd * 64;
    const bf16* k01 = Kpm + ((size_t)b * 1600 + x0 * 40 + y1) * 256 + hd * 64;
    const bf16* k10 = Kpm + ((size_t)b * 1600 + x1 * 40 + y0) * 256 + hd * 64;
    const bf16* k11 = Kpm + ((size_t)b * 1600 + x1 * 40 + y1) * 256 + hd * 64;
    float dot = 0.f;
#pragma unroll
    for (int i = 0; i < 8; ++i) {
      bf16x8 qv = *(const bf16x8*)(Qs + pl * 264 + hd * 64 + i * 8);
      bf16x8 a = *(const bf16x8*)(k00 + i * 8);
      bf16x8 c = *(const bf16x8*)(k01 + i * 8);
      bf16x8 d = *(const bf16x8*)(k10 + i * 8);
      bf16x8 e = *(const bf16x8*)(k11 + i * 8);
#pragma unroll
      for (int j = 0; j < 8; ++j) {
        float kup = w00 * (float)a[j] + w01 * (float)c[j] + w10 * (float)d[j] + w11 * (float)e[j];
        dot += (float)qv[j] * kup;
      }
    }
    score[((size_t)b * 4 + hd) * 6400 + p] = dot * 0.0625f;
  }
}

// ---------------------------------------------------------------------------
// K+V projection (unchanged).
// ---------------------------------------------------------------------------
__global__ __launch_bounds__(512, 1)
void kv_gemm(const float* __restrict__ key,
             const bf16* __restrict__ Wk, const float* __restrict__ bk, bf16* __restrict__ Kpm,
             const bf16* __restrict__ Wv, const float* __restrict__ bv, bf16* __restrict__ Vpm) {
  __shared__ alignas(16) char smem[65536];
  const int P = 1600;
  const int t = threadIdx.x;
  const int b = blockIdx.z;
  const int m0 = blockIdx.x * 128;
  const int sel = blockIdx.y >> 1;
  const int n0 = (blockIdx.y & 1) * 128;
  const bf16* W = sel ? Wv : Wk;
  const float* bias = sel ? bv : bk;
  bf16* out = sel ? Vpm : Kpm;
  const int w = t >> 6, l = t & 63;
  const int wr = w & 1, wc = w >> 1;
  const int lrow = l & 15, koff = (l >> 4) * 8;
  const int up = t & 31, uk = t >> 5;
  const float* actb = key + (size_t)b * 256 * P;

  f32x4 Ar[4];
  f32x4 acc[4][2];
#pragma unroll
  for (int i = 0; i < 4; ++i)
#pragma unroll
    for (int j = 0; j < 2; ++j) acc[i][j] = (f32x4){0.f, 0.f, 0.f, 0.f};

  auto Ab = [&](int buf) { return (bf16*)(smem + buf * 16384); };
  auto Bb = [&](int buf) { return (bf16*)(smem + 32768 + buf * 16384); };

  auto GLOADB = [&](int kt, int buf) {
    const int k0 = kt * 64;
#pragma unroll
    for (int call = 0; call < 2; ++call) {
      int idx = call * 512 + t;
      int row = idx >> 3, u = idx & 7;
      gl16(W + (size_t)(n0 + row) * 256 + k0 + ((u ^ (row & 7)) << 3), Bb(buf) + idx * 8);
    }
  };
  auto ALOAD = [&](int kt) {
    const int k0 = kt * 64;
    int ps = m0 + up * 4;
    if (ps > P - 4) ps = P - 4;
#pragma unroll
    for (int j = 0; j < 4; ++j)
      Ar[j] = *(const f32x4*)(actb + (size_t)(k0 + uk * 4 + j) * P + ps);
  };
  auto ASTORE = [&](int buf) {
#pragma unroll
    for (int j = 0; j < 4; ++j) {
      int row = up * 4 + j;
      int cs = (uk * 4) ^ ((row & 7) << 3);
      bf16x4 v = {(bf16)Ar[0][j], (bf16)Ar[1][j], (bf16)Ar[2][j], (bf16)Ar[3][j]};
      *(bf16x4*)(Ab(buf) + row * 64 + cs) = v;
    }
  };
  auto COMPUTE = [&](int buf) {
#pragma unroll
    for (int kk = 0; kk < 2; ++kk) {
      bf16x8 af[4], bvv[2];
      const int kb = kk * 32 + koff;
#pragma unroll
      for (int i = 0; i < 4; ++i) af[i] = frag(Ab(buf), wr * 64 + i * 16 + lrow, kb);
#pragma unroll
      for (int j = 0; j < 2; ++j) bvv[j] = frag(Bb(buf), wc * 32 + j * 16 + lrow, kb);
#pragma unroll
      for (int i = 0; i < 4; ++i)
#pragma unroll
        for (int j = 0; j < 2; ++j)
          acc[i][j] = __builtin_amdgcn_mfma_f32_16x16x32_bf16(af[i], bvv[j], acc[i][j], 0, 0, 0);
    }
  };

  GLOADB(0, 0);
  ALOAD(0);
  ASTORE(0);
  __syncthreads();
#pragma unroll
  for (int kt = 0; kt < 4; ++kt) {
    const int cur = kt & 1;
    if (kt < 3) { GLOADB(kt + 1, cur ^ 1); ALOAD(kt + 1); }
    __builtin_amdgcn_sched_barrier(0);
    COMPUTE(cur);
    if (kt < 3) ASTORE(cur ^ 1);
    __syncthreads();
  }

  bf16* Sc = (bf16*)smem;
#pragma unroll
  for (int mi = 0; mi < 4; ++mi) {
#pragma unroll
    for (int ni = 0; ni < 2; ++ni) {
      int ch = wc * 32 + ni * 16 + (l & 15);
      float bvf = bias[n0 + ch];
#pragma unroll
      for (int r = 0; r < 4; ++r) {
        int p = wr * 64 + mi * 16 + (l >> 4) * 4 + r;
        Sc[p * 136 + ch] = (bf16)(acc[mi][ni][r] + bvf);
      }
    }
  }
  __syncthreads();
  bf16* ob = out + (size_t)b * P * 256;
#pragma unroll
  for (int pass = 0; pass < 4; ++pass) {
    int unit = pass * 512 + t;
    int row = unit >> 4, cu = unit & 15;
    if (m0 + row < P) {
      bf16x8 v = *(const bf16x8*)(Sc + row * 136 + cu * 8);
      *(bf16x8*)(ob + (size_t)(m0 + row) * 256 + n0 + cu * 8) = v;
    }
  }
}

// ---------------------------------------------------------------------------
// In-place column softmax over x (per b,hd,y), x4 (R2 sum) folded in.
// ---------------------------------------------------------------------------
__global__ void smax_kernel(float* __restrict__ score) {
  __shared__ float s[6400];
  const int hd = blockIdx.x, b = blockIdx.y, t = threadIdx.x;
  float* buf = score + ((size_t)b * 4 + hd) * 6400;
  for (int i = t; i < 6400; i += 256) s[i] = buf[i];
  __syncthreads();
  if (t < 80) {
    const int y = t;
    float m = -1e30f;
    for (int x = 0; x < 80; ++x) m = fmaxf(m, s[x * 80 + y]);
    float sum = 0.f;
    for (int x = 0; x < 80; ++x) {
      float e = __expf(s[x * 80 + y] - m);
      s[x * 80 + y] = e;
      sum += e;
    }
    float inv = 4.0f / sum;
    for (int x = 0; x < 80; ++x) buf[x * 80 + y] = s[x * 80 + y] * inv;
  }
}

// ===========================================================================
// Uv[b][hd][o][q] = sum_{c<64} wo[o][hd*64+c] * V[b][q][hd*64+c]  (unchanged)
// ===========================================================================
__global__ __launch_bounds__(256, 4)
void uv_gemm(const bf16* __restrict__ Vpm, const bf16* __restrict__ Wo,
             bf16* __restrict__ Uv) {
  __shared__ alignas(16) bf16 Vt[64 * 64];
  const int t = threadIdx.x;
  const int b = blockIdx.z;
  const int hd = blockIdx.y;
  const int q0 = blockIdx.x * 64;
  const int w = t >> 6, l = t & 63;
  const int lrow = l & 15, ksel = l >> 4;

  const bf16* vsrc = Vpm + ((size_t)b * 1600 + q0) * 256 + hd * 64;
#pragma unroll
  for (int call = 0; call < 2; ++call) {
    int idx = (w * 2 + call) * 64 + l;
    int q = idx >> 3, u = idx & 7;
    gl16(vsrc + (size_t)q * 256 + ((u ^ (q & 7)) << 3), Vt + idx * 8);
  }
  asm volatile("s_waitcnt vmcnt(0)" ::: "memory");
  __syncthreads();

  f32x4 acc[4][4];
#pragma unroll
  for (int i = 0; i < 4; ++i)
#pragma unroll
    for (int j = 0; j < 4; ++j) acc[i][j] = (f32x4){0.f, 0.f, 0.f, 0.f};

#pragma unroll
  for (int kk = 0; kk < 2; ++kk) {
    bf16x8 af[4], bv[4];
#pragma unroll
    for (int mi = 0; mi < 4; ++mi)
      af[mi] = *(const bf16x8*)(Wo + (size_t)(w * 64 + mi * 16 + lrow) * 256 +
                                hd * 64 + kk * 32 + ksel * 8);
#pragma unroll
    for (int ni = 0; ni < 4; ++ni)
      bv[ni] = frag(Vt, ni * 16 + lrow, kk * 32 + ksel * 8);
#pragma unroll
    for (int mi = 0; mi < 4; ++mi)
#pragma unroll
      for (int ni = 0; ni < 4; ++ni)
        acc[mi][ni] = __builtin_amdgcn_mfma_f32_16x16x32_bf16(af[mi], bv[ni], acc[mi][ni], 0, 0, 0);
  }

  bf16* ob = Uv + ((size_t)(b * 4 + hd)) * 256 * 1600;
#pragma unroll
  for (int mi = 0; mi < 4; ++mi) {
#pragma unroll
    for (int ni = 0; ni < 4; ++ni) {
#pragma unroll
      for (int r = 0; r < 4; ++r) {
        int o = w * 64 + mi * 16 + ksel * 4 + r;
        int q = q0 + ni * 16 + lrow;
        ob[(size_t)o * 1600 + q] = (bf16)acc[mi][ni][r];
      }
    }
  }
}

// ===========================================================================
// combine v2: chunked y (5 x 16) -> small register footprint, NO SPILL.
// d_out[b][o][p] = bo[o] + sum_hd attn[b][hd][p] * bilinear(Uv[b][hd][o])(p)
// Per (chunk, hd): xcv[10] x-interp values (indices compile-time via unroll,
// clamp folded into gather), 16 attn floats, acc16[16]. ~45 live regs.
// ===========================================================================
__global__ __launch_bounds__(256, 2)
void combine(const bf16* __restrict__ Uv, const float* __restrict__ attn,
             const float* __restrict__ bo, float* __restrict__ out) {
  __shared__ bf16 Us[16 * 1600];  // [hd*4+oo][q]
  const int t = threadIdx.x;
  const int b = blockIdx.y;
  const int o0 = blockIdx.x * 4;

  const bf16* usrc = Uv + (size_t)(b * 4) * 256 * 1600;
#pragma unroll
  for (int i = 0; i < 13; ++i) {
    int idx = i * 256 + t;
    if (idx < 3200) {
      int row = idx / 200, u = idx % 200;
      int hd = row >> 2, oo = row & 3;
      bf16x8 v = *(const bf16x8*)(usrc + ((size_t)hd * 256 + o0 + oo) * 1600 + u * 8);
      *(bf16x8*)(Us + row * 1600 + u * 8) = v;
    }
  }
  __syncthreads();
  if (t >= 160) return;
  const int x = t % 80, oh = t / 80;

  float cx = 0.5f * x - 0.25f;
  int ix = (int)floorf(cx);
  float wx1 = cx - ix, wx0 = 1.f - wx1;
  int x0 = ix < 0 ? 0 : ix, x1 = (ix + 1 > 39) ? 39 : ix + 1;

  const float* attb = attn + (size_t)b * 4 * 6400 + x * 80;

  for (int oo2 = 0; oo2 < 2; ++oo2) {
    const int oo = oh * 2 + oo2;
    const float bias = bo[o0 + oo];
    float* op = out + ((size_t)b * 256 + o0 + oo) * 6400 + x * 80;

#pragma unroll
    for (int yc = 0; yc < 80; yc += 16) {
      float acc16[16];
#pragma unroll
      for (int yy = 0; yy < 16; ++yy) acc16[yy] = 0.f;

#pragma unroll
      for (int hd = 0; hd < 4; ++hd) {
        const bf16* r0 = Us + (hd * 4 + oo) * 1600 + x0 * 40;
        const bf16* r1 = Us + (hd * 4 + oo) * 1600 + x1 * 40;
        // x-interp values for q = yc/2-1 .. yc/2+8 (clamped)
        float xcv[10];
#pragma unroll
        for (int i = 0; i < 10; ++i) {
          int qi = yc / 2 - 1 + i;
          qi = qi < 0 ? 0 : (qi > 39 ? 39 : qi);
          xcv[i] = wx0 * (float)r0[qi] + wx1 * (float)r1[qi];
        }
        const float* ah = attb + hd * 6400 + yc;
        f32x4 a0 = *(const f32x4*)(ah);
        f32x4 a1 = *(const f32x4*)(ah + 4);
        f32x4 a2 = *(const f32x4*)(ah + 8);
        f32x4 a3 = *(const f32x4*)(ah + 12);
        float at16[16] = {a0[0], a0[1], a0[2], a0[3], a1[0], a1[1], a1[2], a1[3],
                          a2[0], a2[1], a2[2], a2[3], a3[0], a3[1], a3[2], a3[3]};
#pragma unroll
        for (int yy = 0; yy < 16; ++yy) {
          const int y = yc + yy;
          const int iy = (y == 0) ? -1 : ((y - 1) >> 1);     // true (unclamped) floor index
          const int il = ((yy - 1) >> 1) + 1;                // xcv index of lo (compile-time)
          const float wyh = (0.5f * y - 0.25f) - iy;
          acc16[yy] += at16[yy] * ((1.f - wyh) * xcv[il] + wyh * xcv[il + 1]);
        }
      }
#pragma unroll
      for (int yy = 0; yy < 16; yy += 4) {
        f32x4 v = {acc16[yy] + bias, acc16[yy + 1] + bias,
                   acc16[yy + 2] + bias, acc16[yy + 3] + bias};
        *(f32x4*)(op + yc + yy) = v;
      }
    }
  }
}

// ---------------------------------------------------------------------------
extern "C" void kernel_launch(void* const* d_in, const int* in_sizes, int n_in,
                              void* d_out, int out_size, void* d_ws, size_t ws_size,
                              hipStream_t stream) {
  const float* query = (const float*)d_in[0];
  const float* key   = (const float*)d_in[1];
  const float* wq    = (const float*)d_in[2];
  const float* bq    = (const float*)d_in[3];
  const float* wk    = (const float*)d_in[4];
  const float* bk    = (const float*)d_in[5];
  const float* wv    = (const float*)d_in[6];
  const float* bv    = (const float*)d_in[7];
  const float* wo    = (const float*)d_in[8];
  const float* bo    = (const float*)d_in[9];

  // ws layout (85.7 MB): Uv | Kpm | Vpm | score(+attn in-place) | Wb
  char* ws = (char*)d_ws;
  bf16*  Uv    = (bf16*)(ws);              // 52,428,800 B  [b][hd][o][q]
  bf16*  Kpm   = (bf16*)(ws + 52428800);   // 13,107,200 B
  bf16*  Vpm   = (bf16*)(ws + 65536000);   // 13,107,200 B
  float* score = (float*)(ws + 78643200);  //  6,553,600 B
  bf16*  Wb    = (bf16*)(ws + 85196800);   //    524,288 B: wq,wk,wv,wo bf16
  bf16* wqb = Wb, *wkb = Wb + 65536, *wvb = Wb + 131072, *wob = Wb + 196608;

  wpre<<<dim3(32, 4), 256, 0, stream>>>(wq, wk, wv, wo, Wb);
  kv_gemm<<<dim3(13, 4, 16), 512, 0, stream>>>(key, wkb, bk, Kpm, wvb, bv, Vpm);
  qscore<<<dim3(100, 1, 16), 256, 0, stream>>>(query, wqb, bq, Kpm, score);
  smax_kernel<<<dim3(4, 16), 256, 0, stream>>>(score);
  uv_gemm<<<dim3(25, 4, 16), 256, 0, stream>>>(Vpm, wob, Uv);
  combine<<<dim3(64, 16), 256, 0, stream>>>(Uv, score, bo, (float*)d_out);
}

// Round 13
// 169.976 us; speedup vs baseline: 3.5575x; 1.6111x over previous
//
#include <hip/hip_runtime.h>
#include <hip/hip_bf16.h>

typedef __bf16 bf16;
typedef __attribute__((ext_vector_type(4))) float f32x4;
typedef __attribute__((ext_vector_type(8))) __bf16 bf16x8;
typedef __attribute__((ext_vector_type(4))) __bf16 bf16x4;

// async global->LDS, 16B per lane; LDS dest must be wave-uniform base + lane*16
static __device__ __forceinline__ void gl16(const void* g, void* l) {
  __builtin_amdgcn_global_load_lds((const __attribute__((address_space(1))) void*)g,
                                   (__attribute__((address_space(3))) void*)l, 16, 0, 0);
}
// fragment read from a [*][64] bf16 tile, 16B-unit XOR swizzle by (row&7)
static __device__ __forceinline__ bf16x8 frag(const bf16* tile, int row, int kb) {
  return *(const bf16x8*)(tile + row * 64 + ((((kb) >> 3) ^ (row & 7)) << 3));
}

// ---------------------------------------------------------------------------
// Weight prepass: 4x [256][256] f32 -> bf16 row-major.
// ---------------------------------------------------------------------------
__global__ void wpre(const float* __restrict__ w0, const float* __restrict__ w1,
                     const float* __restrict__ w2, const float* __restrict__ w3,
                     bf16* __restrict__ dst) {
  const float* srcs[4] = {w0, w1, w2, w3};
  const float* s = srcs[blockIdx.y];
  bf16* d = dst + (size_t)blockIdx.y * 65536;
  int base = blockIdx.x * 2048 + threadIdx.x * 8;
  f32x4 a = *(const f32x4*)(s + base);
  f32x4 b = *(const f32x4*)(s + base + 4);
  bf16x8 v = {(bf16)a[0], (bf16)a[1], (bf16)a[2], (bf16)a[3],
              (bf16)b[0], (bf16)b[1], (bf16)b[2], (bf16)b[3]};
  *(bf16x8*)(d + base) = v;
}

// ===========================================================================
// Fused Q-projection + score (unchanged — at structure ceiling).
// ===========================================================================
__global__ __launch_bounds__(256, 3)
void qscore(const float* __restrict__ query, const bf16* __restrict__ Wq,
            const float* __restrict__ bq, const bf16* __restrict__ Kpm,
            float* __restrict__ score) {
  __shared__ alignas(16) char smem[64 * 264 * 2];
  const int t = threadIdx.x;
  const int b = blockIdx.z;
  const int p0 = blockIdx.x * 64;
  const int w = t >> 6, l = t & 63;
  const int lrow = l & 15, ksel = l >> 4;
  const int pq = t & 15, cq = t >> 4;
  const float* actb = query + (size_t)b * 256 * 6400;

  auto Bt = [&](int buf) { return (bf16*)(smem + buf * 8192); };

  f32x4 Ar[4];
  auto ALOAD = [&](int kt) {
    const int k0 = kt * 64;
#pragma unroll
    for (int j = 0; j < 4; ++j)
      Ar[j] = *(const f32x4*)(actb + (size_t)(k0 + cq * 4 + j) * 6400 + p0 + pq * 4);
  };
  auto ASTORE = [&](int buf) {
    bf16* tile = Bt(buf);
#pragma unroll
    for (int e = 0; e < 4; ++e) {
      int row = pq * 4 + e;
      bf16x4 v = {(bf16)Ar[0][e], (bf16)Ar[1][e], (bf16)Ar[2][e], (bf16)Ar[3][e]};
      *(bf16x4*)(tile + row * 64 + ((((cq >> 1) ^ (row & 7)) << 3) | ((cq & 1) << 2))) = v;
    }
  };

  f32x4 acc[4][4];
#pragma unroll
  for (int i = 0; i < 4; ++i)
#pragma unroll
    for (int j = 0; j < 4; ++j) acc[i][j] = (f32x4){0.f, 0.f, 0.f, 0.f};

  auto COMPUTE = [&](int kt, int buf) {
    const int k0 = kt * 64;
    bf16x8 af[4][2];
#pragma unroll
    for (int mi = 0; mi < 4; ++mi)
#pragma unroll
      for (int kk = 0; kk < 2; ++kk)
        af[mi][kk] = *(const bf16x8*)(Wq + (size_t)(w * 64 + mi * 16 + lrow) * 256 +
                                      k0 + kk * 32 + ksel * 8);
    bf16x8 bv[4][2];
#pragma unroll
    for (int ni = 0; ni < 4; ++ni)
#pragma unroll
      for (int kk = 0; kk < 2; ++kk)
        bv[ni][kk] = frag(Bt(buf), ni * 16 + lrow, kk * 32 + ksel * 8);
#pragma unroll
    for (int kk = 0; kk < 2; ++kk)
#pragma unroll
      for (int mi = 0; mi < 4; ++mi)
#pragma unroll
        for (int ni = 0; ni < 4; ++ni)
          acc[mi][ni] = __builtin_amdgcn_mfma_f32_16x16x32_bf16(af[mi][kk], bv[ni][kk],
                                                                acc[mi][ni], 0, 0, 0);
  };

  ALOAD(0);
  ASTORE(0);
  __syncthreads();
#pragma unroll
  for (int kt = 0; kt < 4; ++kt) {
    if (kt < 3) ALOAD(kt + 1);
    COMPUTE(kt, kt & 1);
    if (kt < 3) ASTORE((kt + 1) & 1);
    __syncthreads();
  }

  __syncthreads();
  bf16* Qs = (bf16*)smem;
#pragma unroll
  for (int mi = 0; mi < 4; ++mi) {
#pragma unroll
    for (int r = 0; r < 4; ++r) {
      int o = w * 64 + mi * 16 + ksel * 4 + r;
      float bvf = bq[o];
#pragma unroll
      for (int ni = 0; ni < 4; ++ni) {
        int px = ni * 16 + lrow;
        Qs[px * 264 + o] = (bf16)(acc[mi][ni][r] + bvf);
      }
    }
  }
  __syncthreads();

  {
    int pl = t & 63, hd = t >> 6;
    int p = p0 + pl;
    int x = p / 80, y = p % 80;
    float cx = 0.5f * x - 0.25f;
    int ix = (int)floorf(cx);
    float wx1 = cx - ix;
    int x0 = ix < 0 ? 0 : ix, x1 = (ix + 1 > 39) ? 39 : ix + 1;
    float cy = 0.5f * y - 0.25f;
    int iy = (int)floorf(cy);
    float wy1 = cy - iy;
    int y0 = iy < 0 ? 0 : iy, y1 = (iy + 1 > 39) ? 39 : iy + 1;
    float w00 = (1.f - wx1) * (1.f - wy1), w01 = (1.f - wx1) * wy1;
    float w10 = wx1 * (1.f - wy1), w11 = wx1 * wy1;
    const bf16* k00 = Kpm + ((size_t)b * 1600 + x0 * 40 + y0) * 256 + hd * 64;
    const bf16* k01 = Kpm + ((size_t)b * 1600 + x0 * 40 + y1) * 256 + hd * 64;
    const bf16* k10 = Kpm + ((size_t)b * 1600 + x1 * 40 + y0) * 256 + hd * 64;
    const bf16* k11 = Kpm + ((size_t)b * 1600 + x1 * 40 + y1) * 256 + hd * 64;
    float dot = 0.f;
#pragma unroll
    for (int i = 0; i < 8; ++i) {
      bf16x8 qv = *(const bf16x8*)(Qs + pl * 264 + hd * 64 + i * 8);
      bf16x8 a = *(const bf16x8*)(k00 + i * 8);
      bf16x8 c = *(const bf16x8*)(k01 + i * 8);
      bf16x8 d = *(const bf16x8*)(k10 + i * 8);
      bf16x8 e = *(const bf16x8*)(k11 + i * 8);
#pragma unroll
      for (int j = 0; j < 8; ++j) {
        float kup = w00 * (float)a[j] + w01 * (float)c[j] + w10 * (float)d[j] + w11 * (float)e[j];
        dot += (float)qv[j] * kup;
      }
    }
    score[((size_t)b * 4 + hd) * 6400 + p] = dot * 0.0625f;
  }
}

// ---------------------------------------------------------------------------
// K+V projection (unchanged).
// ---------------------------------------------------------------------------
__global__ __launch_bounds__(512, 1)
void kv_gemm(const float* __restrict__ key,
             const bf16* __restrict__ Wk, const float* __restrict__ bk, bf16* __restrict__ Kpm,
             const bf16* __restrict__ Wv, const float* __restrict__ bv, bf16* __restrict__ Vpm) {
  __shared__ alignas(16) char smem[65536];
  const int P = 1600;
  const int t = threadIdx.x;
  const int b = blockIdx.z;
  const int m0 = blockIdx.x * 128;
  const int sel = blockIdx.y >> 1;
  const int n0 = (blockIdx.y & 1) * 128;
  const bf16* W = sel ? Wv : Wk;
  const float* bias = sel ? bv : bk;
  bf16* out = sel ? Vpm : Kpm;
  const int w = t >> 6, l = t & 63;
  const int wr = w & 1, wc = w >> 1;
  const int lrow = l & 15, koff = (l >> 4) * 8;
  const int up = t & 31, uk = t >> 5;
  const float* actb = key + (size_t)b * 256 * P;

  f32x4 Ar[4];
  f32x4 acc[4][2];
#pragma unroll
  for (int i = 0; i < 4; ++i)
#pragma unroll
    for (int j = 0; j < 2; ++j) acc[i][j] = (f32x4){0.f, 0.f, 0.f, 0.f};

  auto Ab = [&](int buf) { return (bf16*)(smem + buf * 16384); };
  auto Bb = [&](int buf) { return (bf16*)(smem + 32768 + buf * 16384); };

  auto GLOADB = [&](int kt, int buf) {
    const int k0 = kt * 64;
#pragma unroll
    for (int call = 0; call < 2; ++call) {
      int idx = call * 512 + t;
      int row = idx >> 3, u = idx & 7;
      gl16(W + (size_t)(n0 + row) * 256 + k0 + ((u ^ (row & 7)) << 3), Bb(buf) + idx * 8);
    }
  };
  auto ALOAD = [&](int kt) {
    const int k0 = kt * 64;
    int ps = m0 + up * 4;
    if (ps > P - 4) ps = P - 4;
#pragma unroll
    for (int j = 0; j < 4; ++j)
      Ar[j] = *(const f32x4*)(actb + (size_t)(k0 + uk * 4 + j) * P + ps);
  };
  auto ASTORE = [&](int buf) {
#pragma unroll
    for (int j = 0; j < 4; ++j) {
      int row = up * 4 + j;
      int cs = (uk * 4) ^ ((row & 7) << 3);
      bf16x4 v = {(bf16)Ar[0][j], (bf16)Ar[1][j], (bf16)Ar[2][j], (bf16)Ar[3][j]};
      *(bf16x4*)(Ab(buf) + row * 64 + cs) = v;
    }
  };
  auto COMPUTE = [&](int buf) {
#pragma unroll
    for (int kk = 0; kk < 2; ++kk) {
      bf16x8 af[4], bvv[2];
      const int kb = kk * 32 + koff;
#pragma unroll
      for (int i = 0; i < 4; ++i) af[i] = frag(Ab(buf), wr * 64 + i * 16 + lrow, kb);
#pragma unroll
      for (int j = 0; j < 2; ++j) bvv[j] = frag(Bb(buf), wc * 32 + j * 16 + lrow, kb);
#pragma unroll
      for (int i = 0; i < 4; ++i)
#pragma unroll
        for (int j = 0; j < 2; ++j)
          acc[i][j] = __builtin_amdgcn_mfma_f32_16x16x32_bf16(af[i], bvv[j], acc[i][j], 0, 0, 0);
    }
  };

  GLOADB(0, 0);
  ALOAD(0);
  ASTORE(0);
  __syncthreads();
#pragma unroll
  for (int kt = 0; kt < 4; ++kt) {
    const int cur = kt & 1;
    if (kt < 3) { GLOADB(kt + 1, cur ^ 1); ALOAD(kt + 1); }
    __builtin_amdgcn_sched_barrier(0);
    COMPUTE(cur);
    if (kt < 3) ASTORE(cur ^ 1);
    __syncthreads();
  }

  bf16* Sc = (bf16*)smem;
#pragma unroll
  for (int mi = 0; mi < 4; ++mi) {
#pragma unroll
    for (int ni = 0; ni < 2; ++ni) {
      int ch = wc * 32 + ni * 16 + (l & 15);
      float bvf = bias[n0 + ch];
#pragma unroll
      for (int r = 0; r < 4; ++r) {
        int p = wr * 64 + mi * 16 + (l >> 4) * 4 + r;
        Sc[p * 136 + ch] = (bf16)(acc[mi][ni][r] + bvf);
      }
    }
  }
  __syncthreads();
  bf16* ob = out + (size_t)b * P * 256;
#pragma unroll
  for (int pass = 0; pass < 4; ++pass) {
    int unit = pass * 512 + t;
    int row = unit >> 4, cu = unit & 15;
    if (m0 + row < P) {
      bf16x8 v = *(const bf16x8*)(Sc + row * 136 + cu * 8);
      *(bf16x8*)(ob + (size_t)(m0 + row) * 256 + n0 + cu * 8) = v;
    }
  }
}

// ---------------------------------------------------------------------------
// In-place column softmax over x (per b,hd,y), x4 (R2 sum) folded in.
// ---------------------------------------------------------------------------
__global__ void smax_kernel(float* __restrict__ score) {
  __shared__ float s[6400];
  const int hd = blockIdx.x, b = blockIdx.y, t = threadIdx.x;
  float* buf = score + ((size_t)b * 4 + hd) * 6400;
  for (int i = t; i < 6400; i += 256) s[i] = buf[i];
  __syncthreads();
  if (t < 80) {
    const int y = t;
    float m = -1e30f;
    for (int x = 0; x < 80; ++x) m = fmaxf(m, s[x * 80 + y]);
    float sum = 0.f;
    for (int x = 0; x < 80; ++x) {
      float e = __expf(s[x * 80 + y] - m);
      s[x * 80 + y] = e;
      sum += e;
    }
    float inv = 4.0f / sum;
    for (int x = 0; x < 80; ++x) buf[x * 80 + y] = s[x * 80 + y] * inv;
  }
}

// ===========================================================================
// Uv[b][hd][o][q] = sum_{c<64} wo[o][hd*64+c] * V[b][q][hd*64+c]  (unchanged)
// ===========================================================================
__global__ __launch_bounds__(256, 4)
void uv_gemm(const bf16* __restrict__ Vpm, const bf16* __restrict__ Wo,
             bf16* __restrict__ Uv) {
  __shared__ alignas(16) bf16 Vt[64 * 64];
  const int t = threadIdx.x;
  const int b = blockIdx.z;
  const int hd = blockIdx.y;
  const int q0 = blockIdx.x * 64;
  const int w = t >> 6, l = t & 63;
  const int lrow = l & 15, ksel = l >> 4;

  const bf16* vsrc = Vpm + ((size_t)b * 1600 + q0) * 256 + hd * 64;
#pragma unroll
  for (int call = 0; call < 2; ++call) {
    int idx = (w * 2 + call) * 64 + l;
    int q = idx >> 3, u = idx & 7;
    gl16(vsrc + (size_t)q * 256 + ((u ^ (q & 7)) << 3), Vt + idx * 8);
  }
  asm volatile("s_waitcnt vmcnt(0)" ::: "memory");
  __syncthreads();

  f32x4 acc[4][4];
#pragma unroll
  for (int i = 0; i < 4; ++i)
#pragma unroll
    for (int j = 0; j < 4; ++j) acc[i][j] = (f32x4){0.f, 0.f, 0.f, 0.f};

#pragma unroll
  for (int kk = 0; kk < 2; ++kk) {
    bf16x8 af[4], bv[4];
#pragma unroll
    for (int mi = 0; mi < 4; ++mi)
      af[mi] = *(const bf16x8*)(Wo + (size_t)(w * 64 + mi * 16 + lrow) * 256 +
                                hd * 64 + kk * 32 + ksel * 8);
#pragma unroll
    for (int ni = 0; ni < 4; ++ni)
      bv[ni] = frag(Vt, ni * 16 + lrow, kk * 32 + ksel * 8);
#pragma unroll
    for (int mi = 0; mi < 4; ++mi)
#pragma unroll
      for (int ni = 0; ni < 4; ++ni)
        acc[mi][ni] = __builtin_amdgcn_mfma_f32_16x16x32_bf16(af[mi], bv[ni], acc[mi][ni], 0, 0, 0);
  }

  bf16* ob = Uv + ((size_t)(b * 4 + hd)) * 256 * 1600;
#pragma unroll
  for (int mi = 0; mi < 4; ++mi) {
#pragma unroll
    for (int ni = 0; ni < 4; ++ni) {
#pragma unroll
      for (int r = 0; r < 4; ++r) {
        int o = w * 64 + mi * 16 + ksel * 4 + r;
        int q = q0 + ni * 16 + lrow;
        ob[(size_t)o * 1600 + q] = (bf16)acc[mi][ni][r];
      }
    }
  }
}

// ===========================================================================
// combine v3: one block per (o, b) -> fully coalesced output writes.
// d_out[b][o][p] = bo[o] + sum_hd attn[b][hd][p] * bilerp(Uv[b][hd][o])(p)
// Stage 4 Uv rows (12.8KB LDS) + interp tables; thread t walks p = t+256*i:
// 4 LDS gathers + coalesced attn load per head, contiguous f32 store.
// Each Uv element is read exactly once chip-wide.
// ===========================================================================
__global__ __launch_bounds__(256, 8)
void combine(const bf16* __restrict__ Uv, const float* __restrict__ attn,
             const float* __restrict__ bo, float* __restrict__ out) {
  __shared__ bf16 Us[4][1600];
  __shared__ int   sx0[80], sx1[80];
  __shared__ float swx[80];
  const int t = threadIdx.x;
  const int o = blockIdx.x;
  const int b = blockIdx.y;

  const bf16* usrc = Uv + (size_t)(b * 4) * 256 * 1600 + (size_t)o * 1600;
  for (int idx = t; idx < 800; idx += 256) {
    int hd = idx / 200, u = idx % 200;
    *(bf16x8*)&Us[hd][u * 8] = *(const bf16x8*)(usrc + (size_t)hd * 256 * 1600 + u * 8);
  }
  if (t < 80) {
    float c = 0.5f * t - 0.25f;
    int i0 = (int)floorf(c);
    swx[t] = c - i0;                       // frac weight toward hi
    sx0[t] = i0 < 0 ? 0 : i0;
    sx1[t] = (i0 + 1 > 39) ? 39 : i0 + 1;
  }
  __syncthreads();

  const float bias = bo[o];
  const float* attb = attn + (size_t)b * 4 * 6400;
  float* op = out + ((size_t)b * 256 + o) * 6400;

  for (int p = t; p < 6400; p += 256) {
    int x = p / 80, y = p - x * 80;
    int x0 = sx0[x], x1 = sx1[x], y0 = sx0[y], y1 = sx1[y];
    float wx1 = swx[x], wy1 = swx[y];
    float w00 = (1.f - wx1) * (1.f - wy1), w01 = (1.f - wx1) * wy1;
    float w10 = wx1 * (1.f - wy1), w11 = wx1 * wy1;
    int q00 = x0 * 40 + y0, q01 = x0 * 40 + y1, q10 = x1 * 40 + y0, q11 = x1 * 40 + y1;
    float acc = bias;
#pragma unroll
    for (int hd = 0; hd < 4; ++hd) {
      float up = w00 * (float)Us[hd][q00] + w01 * (float)Us[hd][q01] +
                 w10 * (float)Us[hd][q10] + w11 * (float)Us[hd][q11];
      acc += attb[hd * 6400 + p] * up;
    }
    op[p] = acc;
  }
}

// ---------------------------------------------------------------------------
extern "C" void kernel_launch(void* const* d_in, const int* in_sizes, int n_in,
                              void* d_out, int out_size, void* d_ws, size_t ws_size,
                              hipStream_t stream) {
  const float* query = (const float*)d_in[0];
  const float* key   = (const float*)d_in[1];
  const float* wq    = (const float*)d_in[2];
  const float* bq    = (const float*)d_in[3];
  const float* wk    = (const float*)d_in[4];
  const float* bk    = (const float*)d_in[5];
  const float* wv    = (const float*)d_in[6];
  const float* bv    = (const float*)d_in[7];
  const float* wo    = (const float*)d_in[8];
  const float* bo    = (const float*)d_in[9];

  // ws layout (85.7 MB): Uv | Kpm | Vpm | score(+attn in-place) | Wb
  char* ws = (char*)d_ws;
  bf16*  Uv    = (bf16*)(ws);              // 52,428,800 B  [b][hd][o][q]
  bf16*  Kpm   = (bf16*)(ws + 52428800);   // 13,107,200 B
  bf16*  Vpm   = (bf16*)(ws + 65536000);   // 13,107,200 B
  float* score = (float*)(ws + 78643200);  //  6,553,600 B
  bf16*  Wb    = (bf16*)(ws + 85196800);   //    524,288 B: wq,wk,wv,wo bf16
  bf16* wqb = Wb, *wkb = Wb + 65536, *wvb = Wb + 131072, *wob = Wb + 196608;

  wpre<<<dim3(32, 4), 256, 0, stream>>>(wq, wk, wv, wo, Wb);
  kv_gemm<<<dim3(13, 4, 16), 512, 0, stream>>>(key, wkb, bk, Kpm, wvb, bv, Vpm);
  qscore<<<dim3(100, 1, 16), 256, 0, stream>>>(query, wqb, bq, Kpm, score);
  smax_kernel<<<dim3(4, 16), 256, 0, stream>>>(score);
  uv_gemm<<<dim3(25, 4, 16), 256, 0, stream>>>(Vpm, wob, Uv);
  combine<<<dim3(256, 16), 256, 0, stream>>>(Uv, score, bo, (float*)d_out);
}